// Round 4
// baseline (301.484 us; speedup 1.0000x reference)
//
#include <hip/hip_runtime.h>
#include <math.h>

#define NBLK 256

__device__ __forceinline__ float4 f4max(float4 a, float4 b) {
    return make_float4(fmaxf(a.x, b.x), fmaxf(a.y, b.y), fmaxf(a.z, b.z), fmaxf(a.w, b.w));
}
__device__ __forceinline__ float4 f4scale(float s, float4 v) {
    return make_float4(s * v.x, s * v.y, s * v.z, s * v.w);
}
__device__ __forceinline__ float4 f4add(float4 a, float4 b) {
    return make_float4(a.x + b.x, a.y + b.y, a.z + b.z, a.w + b.w);
}
__device__ __forceinline__ float4 f4fma(float a, float4 b, float4 c) {  // scalar*vec+vec
    return make_float4(fmaf(a, b.x, c.x), fmaf(a, b.y, c.y), fmaf(a, b.z, c.z), fmaf(a, b.w, c.w));
}
__device__ __forceinline__ float4 f4fma4(float4 a, float4 b, float4 c) { // elementwise
    return make_float4(fmaf(a.x, b.x, c.x), fmaf(a.y, b.y, c.y),
                       fmaf(a.z, b.z, c.z), fmaf(a.w, b.w, c.w));
}

// Generation grid barrier. counter must start at 0 (memset by host); gen any value.
// Release: __threadfence (agent wbl2) before arrive; acquire: gen load + __threadfence
// (agent buffer_inv) after. Cross-XCD safe per agent-scope fence semantics.
__device__ __forceinline__ void grid_barrier(int* counter, int* gen) {
    __syncthreads();
    if (threadIdx.x == 0) {
        __threadfence();   // release: drain + writeback this XCD's dirty L2
        int g = __hip_atomic_load(gen, __ATOMIC_RELAXED, __HIP_MEMORY_SCOPE_AGENT);
        int t = __hip_atomic_fetch_add(counter, 1, __ATOMIC_ACQ_REL, __HIP_MEMORY_SCOPE_AGENT);
        if (t == NBLK - 1) {
            __hip_atomic_store(counter, 0, __ATOMIC_RELAXED, __HIP_MEMORY_SCOPE_AGENT);
            __hip_atomic_fetch_add(gen, 1, __ATOMIC_RELEASE, __HIP_MEMORY_SCOPE_AGENT);
        } else {
            while (__hip_atomic_load(gen, __ATOMIC_ACQUIRE, __HIP_MEMORY_SCOPE_AGENT) == g)
                __builtin_amdgcn_s_sleep(2);
        }
        __threadfence();   // acquire: invalidate stale L1/L2 before reading others' data
    }
    __syncthreads();
}

// Wave-level sparsemax (verified R2): lane holds element `lane` of a 64-vector.
__device__ __forceinline__ float wave_sparsemax(float z, int lane) {
    float v = z;
    for (int k = 2; k <= 64; k <<= 1) {
        bool desc = (lane & k) == 0;
        for (int j = k >> 1; j > 0; j >>= 1) {
            float other = __shfl_xor(v, j, 64);
            bool lower = (lane & j) == 0;
            float mn = fminf(v, other), mx = fmaxf(v, other);
            v = (desc ^ lower) ? mn : mx;
        }
    }
    float c = v;
    for (int d = 1; d < 64; d <<= 1) {
        float n = __shfl_up(c, d, 64);
        if (lane >= d) c += n;
    }
    bool sup = (1.0f + (float)(lane + 1) * v) > c;
    int ksel = __popcll(__ballot(sup));
    float zk = __shfl(c, ksel - 1, 64);
    float tau = (zk - 1.0f) / (float)ksel;
    return fmaxf(z - tau, 0.f);
}

__global__ __launch_bounds__(256)
void mono_kernel(const float* __restrict__ x, const float* __restrict__ W0,
                 const float* __restrict__ W1, const float* __restrict__ Wp,
                 float* __restrict__ out, float* __restrict__ P,
                 float* __restrict__ adj0, float* __restrict__ h0,
                 float* __restrict__ adj1, int* __restrict__ bar) {
    __shared__ __align__(16) float smem[16384];   // 64 KB, reused per phase
    const int tid = threadIdx.x;
    const int lane = tid & 63;
    const int bid = blockIdx.x;
    int* counter = bar;
    int* gen = bar + 1;

    // ---------------- Phase 1: gram0 partials. Block c: P[c][i][j] over K-chunk c.
    {
        float (*xsT)[68] = (float (*)[68])smem;
        int k0 = bid * 64;
#pragma unroll
        for (int it = 0; it < 4; ++it) {
            int f = it * 256 + tid;
            int i = f >> 4, k4 = (f & 15) * 4;
            float4 v = *(const float4*)(x + (size_t)i * 16384 + k0 + k4);
            xsT[k4 + 0][i] = v.x; xsT[k4 + 1][i] = v.y;
            xsT[k4 + 2][i] = v.z; xsT[k4 + 3][i] = v.w;
        }
        __syncthreads();
        int ti = (tid >> 4) * 4, tj = (tid & 15) * 4;
        float4 a0 = make_float4(0, 0, 0, 0), a1 = a0, a2 = a0, a3 = a0;
#pragma unroll 8
        for (int k = 0; k < 64; ++k) {
            float4 a = *(const float4*)&xsT[k][ti];
            float4 b = *(const float4*)&xsT[k][tj];
            a0 = f4fma(a.x, b, a0); a1 = f4fma(a.y, b, a1);
            a2 = f4fma(a.z, b, a2); a3 = f4fma(a.w, b, a3);
        }
        float* basep = P + ((size_t)bid << 12);
        *(float4*)(basep + (ti + 0) * 64 + tj) = a0;
        *(float4*)(basep + (ti + 1) * 64 + tj) = a1;
        *(float4*)(basep + (ti + 2) * 64 + tj) = a2;
        *(float4*)(basep + (ti + 3) * 64 + tj) = a3;
    }
    grid_barrier(counter, gen);

    // ---------------- Phase 2: reduce 256 chunks + sparsemax -> adj0. Blocks 0..63.
    if (bid < 64) {
        float* red = smem;   // [4][64]
        int w = tid >> 6;
        float s = 0.f;
        for (int c = w * 64; c < (w + 1) * 64; ++c)
            s += P[((size_t)c << 12) + bid * 64 + lane];
        red[w * 64 + lane] = s;
        __syncthreads();
        if (tid < 64) {
            float z = (red[lane] + red[64 + lane] + red[128 + lane] + red[192 + lane])
                      * (1.0f / 256.0f);
            adj0[bid * 64 + lane] = wave_sparsemax(z, lane);
        }
    }
    grid_barrier(counter, gen);

    // ---------------- Phase 3: agg0 + W0 projection + relu -> h0.
    // Block = (t-chunk of 4) x (16 B's, 2 passes x 4 waves x 2 B).
    {
        int t0 = (bid >> 2) * 4;
        int BcB = (bid & 3) * 16;
#pragma unroll
        for (int it = 0; it < 16; ++it) {
            int f = it * 256 + tid;
            int b = f >> 6, tt = (f >> 4) & 3, e4 = (f & 15) * 4;
            *(float4*)&smem[(b * 4 + tt) * 64 + e4] =
                *(const float4*)(x + ((size_t)(b * 256 + t0 + tt) * 64 + e4));
        }
        __syncthreads();
        int w = __builtin_amdgcn_readfirstlane(tid >> 6);
        int t = lane >> 4, eq = lane & 15;
        float4 w0r0 = *(const float4*)(W0 + (eq * 4 + 0) * 4);
        float4 w0r1 = *(const float4*)(W0 + (eq * 4 + 1) * 4);
        float4 w0r2 = *(const float4*)(W0 + (eq * 4 + 2) * 4);
        float4 w0r3 = *(const float4*)(W0 + (eq * 4 + 3) * 4);
        const float4* xsp = (const float4*)smem;
#pragma unroll
        for (int pass = 0; pass < 2; ++pass) {
            int Bp = BcB + pass * 8 + w * 2;
            const float* pA = adj0 + Bp * 64;   // uniform -> s_load (safe: first touch
            const float* pB = pA + 64;          // post-barrier, acquire did buffer_inv)
            // v[b] = p[b]*x4[b]; win[b] = max(q[b-1], q[b+1]), q[b] = max(v[b],v[b+1])
            float4 x4 = xsp[(0 * 4 + t) * 16 + eq];
            float4 vA = f4scale(pA[0], x4), vB = f4scale(pB[0], x4);
            float4 qm1A = vA, qm1B = vB;
            x4 = xsp[(1 * 4 + t) * 16 + eq];
            float4 vtA = f4scale(pA[1], x4), vtB = f4scale(pB[1], x4);
            float4 qbA = f4max(vA, vtA), qbB = f4max(vB, vtB);
            float4 accA = make_float4(0, 0, 0, 0), accB = accA;
#pragma unroll 8
            for (int bl = 0; bl < 62; ++bl) {
                x4 = xsp[((bl + 2) * 4 + t) * 16 + eq];
                float4 vnA = f4scale(pA[bl + 2], x4);
                float4 vnB = f4scale(pB[bl + 2], x4);
                float4 q1A = f4max(vtA, vnA), q1B = f4max(vtB, vnB);
                accA = f4add(accA, f4max(qm1A, q1A));
                accB = f4add(accB, f4max(qm1B, q1B));
                qm1A = qbA; qbA = q1A; vtA = vnA;
                qm1B = qbB; qbB = q1B; vtB = vnB;
            }
            accA = f4add(accA, f4max(qm1A, vtA));   // win[62] = max(q61, q63)
            accB = f4add(accB, f4max(qm1B, vtB));
            accA = f4add(accA, qbA);                // win[63] = q62
            accB = f4add(accB, qbB);
#pragma unroll
            for (int half = 0; half < 2; ++half) {
                float4 acc = half ? accB : accA;
                float4 h = f4fma(acc.x, w0r0, f4fma(acc.y, w0r1,
                           f4fma(acc.z, w0r2, f4scale(acc.w, w0r3))));
                for (int m = 1; m <= 8; m <<= 1) {
                    h.x += __shfl_xor(h.x, m, 64);
                    h.y += __shfl_xor(h.y, m, 64);
                    h.z += __shfl_xor(h.z, m, 64);
                    h.w += __shfl_xor(h.w, m, 64);
                }
                if (eq == 0) {
                    float4 r = make_float4(fmaxf(h.x, 0.f), fmaxf(h.y, 0.f),
                                           fmaxf(h.z, 0.f), fmaxf(h.w, 0.f));
                    *(float4*)(h0 + (size_t)((Bp + half) * 256 + t0 + t) * 4) = r;
                }
            }
        }
    }
    grid_barrier(counter, gen);

    // ---------------- Phase 4: gram1 (direct) + sparsemax -> adj1. Blocks 0..63.
    if (bid < 64) {
        float* row = smem;          // 1024 floats: h0[i,:]
        float* part = smem + 1024;  // 256 partials
        *(float4*)(row + tid * 4) = *(const float4*)(h0 + (size_t)bid * 1024 + tid * 4);
        __syncthreads();
        int j = tid >> 2, q = tid & 3;
        const float4* hj = (const float4*)(h0 + (size_t)j * 1024 + q * 256);
        const float4* ri = (const float4*)(row + q * 256);
        float4 s4 = make_float4(0, 0, 0, 0);
#pragma unroll 8
        for (int kk = 0; kk < 64; ++kk) s4 = f4fma4(ri[kk], hj[kk], s4);
        part[tid] = s4.x + s4.y + s4.z + s4.w;
        __syncthreads();
        if (tid < 64) {
            float z = (part[lane * 4] + part[lane * 4 + 1] + part[lane * 4 + 2]
                       + part[lane * 4 + 3]) * (1.0f / 256.0f);
            adj1[bid * 64 + lane] = wave_sparsemax(z, lane);
        }
    }
    grid_barrier(counter, gen);

    // ---------------- Phase 5: agg1 + W1 + relu + mean_t + softmax -> out. Blocks 0..63.
    if (bid < 64) {
        int w = __builtin_amdgcn_readfirstlane(tid >> 6);
        int rc = lane & 3;
        const float* prow = adj1 + bid * 64;   // uniform
        float psum = 0.f;
#pragma unroll
        for (int gg = 0; gg < 4; ++gg) {
            int tbase = w * 64 + gg * 16;
            const float* xb = h0 + (size_t)tbase * 4 + lane;
            float v0 = prow[0] * xb[0];
            float v1 = prow[1] * xb[1024];
            float qm1 = v0, qb = fmaxf(v0, v1), vt = v1, acc = 0.f;
#pragma unroll 8
            for (int bl = 0; bl < 62; ++bl) {
                float vn = prow[bl + 2] * xb[(size_t)(bl + 2) * 1024];
                float q1 = fmaxf(vt, vn);
                acc += fmaxf(qm1, q1);
                qm1 = qb; qb = q1; vt = vn;
            }
            acc += fmaxf(qm1, vt);
            acc += qb;
            int base = lane & ~3;
            float b0 = __shfl(acc, base + 0, 64);
            float b1 = __shfl(acc, base + 1, 64);
            float b2 = __shfl(acc, base + 2, 64);
            float b3 = __shfl(acc, base + 3, 64);
            float h = b0 * W1[rc] + b1 * W1[4 + rc] + b2 * W1[8 + rc] + b3 * W1[12 + rc];
            psum += fmaxf(h, 0.f);
        }
        for (int m = 4; m <= 32; m <<= 1) psum += __shfl_xor(psum, m, 64);
        __syncthreads();                      // smem free from phase 4
        if (lane < 4) smem[w * 4 + lane] = psum;
        __syncthreads();
        if (tid < 64) {
            float pooled = 0.f;
            if (lane < 4)
                pooled = (smem[lane] + smem[4 + lane] + smem[8 + lane] + smem[12 + lane])
                         * (1.0f / 256.0f);
            float q0 = __shfl(pooled, 0, 64), q1 = __shfl(pooled, 1, 64);
            float q2 = __shfl(pooled, 2, 64), q3 = __shfl(pooled, 3, 64);
            float logit = -INFINITY;
            if (lane < 8)
                logit = q0 * Wp[lane] + q1 * Wp[8 + lane]
                      + q2 * Wp[16 + lane] + q3 * Wp[24 + lane];
            float mx = logit;
            for (int m = 4; m >= 1; m >>= 1) mx = fmaxf(mx, __shfl_xor(mx, m, 8));
            float e = (lane < 8) ? __expf(logit - mx) : 0.f;
            float s = e;
            for (int m = 4; m >= 1; m >>= 1) s += __shfl_xor(s, m, 8);
            if (lane < 8) out[bid * 8 + lane] = e / s;
        }
    }
}

extern "C" void kernel_launch(void* const* d_in, const int* in_sizes, int n_in,
                              void* d_out, int out_size, void* d_ws, size_t ws_size,
                              hipStream_t stream) {
    const float* x  = (const float*)d_in[0];   // [64,256,64]
    const float* W0 = (const float*)d_in[1];   // [64,4]
    const float* W1 = (const float*)d_in[2];   // [4,4]
    const float* Wp = (const float*)d_in[3];   // [4,8]
    float* out = (float*)d_out;                // [64,8]

    char* ws = (char*)d_ws;
    float* P    = (float*)(ws);                              // 4 MB partials
    float* adj0 = (float*)(ws + (4u << 20));                 // 16 KB
    float* h0   = (float*)(ws + (4u << 20) + 16384);         // 256 KB
    float* adj1 = (float*)(ws + (4u << 20) + 16384 + 262144);// 16 KB
    int*   bar  = (int*)  (ws + (4u << 20) + 2 * 16384 + 262144);

    hipMemsetAsync(bar, 0, 64, stream);   // barrier counter+gen must start at 0
    mono_kernel<<<NBLK, 256, 0, stream>>>(x, W0, W1, Wp, out, P, adj0, h0, adj1, bar);
}

// Round 6
// 130.904 us; speedup vs baseline: 2.3031x; 2.3031x over previous
//
#include <hip/hip_runtime.h>
#include <math.h>

__device__ __forceinline__ float4 f4max(float4 a, float4 b) {
    return make_float4(fmaxf(a.x, b.x), fmaxf(a.y, b.y), fmaxf(a.z, b.z), fmaxf(a.w, b.w));
}
__device__ __forceinline__ float4 f4scale(float s, float4 v) {
    return make_float4(s * v.x, s * v.y, s * v.z, s * v.w);
}
__device__ __forceinline__ float4 f4add(float4 a, float4 b) {
    return make_float4(a.x + b.x, a.y + b.y, a.z + b.z, a.w + b.w);
}
__device__ __forceinline__ float4 f4fma(float a, float4 b, float4 c) {  // scalar*vec+vec
    return make_float4(fmaf(a, b.x, c.x), fmaf(a, b.y, c.y), fmaf(a, b.z, c.z), fmaf(a, b.w, c.w));
}
__device__ __forceinline__ float4 f4fma4(float4 a, float4 b, float4 c) { // elementwise
    return make_float4(fmaf(a.x, b.x, c.x), fmaf(a.y, b.y, c.y),
                       fmaf(a.z, b.z, c.z), fmaf(a.w, b.w, c.w));
}

// Wave-level sparsemax (verified R2-R4): lane holds element `lane` of a 64-vector.
__device__ __forceinline__ float wave_sparsemax(float z, int lane) {
    float v = z;
    for (int k = 2; k <= 64; k <<= 1) {
        bool desc = (lane & k) == 0;
        for (int j = k >> 1; j > 0; j >>= 1) {
            float other = __shfl_xor(v, j, 64);
            bool lower = (lane & j) == 0;
            float mn = fminf(v, other), mx = fmaxf(v, other);
            v = (desc ^ lower) ? mn : mx;
        }
    }
    float c = v;
    for (int d = 1; d < 64; d <<= 1) {
        float n = __shfl_up(c, d, 64);
        if (lane >= d) c += n;
    }
    bool sup = (1.0f + (float)(lane + 1) * v) > c;
    int ksel = __popcll(__ballot(sup));
    float zk = __shfl(c, ksel - 1, 64);
    float tau = (zk - 1.0f) / (float)ksel;
    return fmaxf(z - tau, 0.f);
}

// ---------------------------------------------------------------------------
// K1: adjraw[i][j] += sum_{k in chunk bid} X[i][k]X[j][k]  (atomicAdd K-split).
// LDS-tiled (verified R3 structure), 4x4 register tile per thread.
// Atomic ordering is safe: layer-0 sparsemax saturates to exact one-hot
// (diag ~64 vs off-diag ~0.5), and sparsemax is 1-Lipschitz regardless.
// ---------------------------------------------------------------------------
__global__ __launch_bounds__(256)
void gram0_kernel(const float* __restrict__ X, float* __restrict__ adjraw) {
    __shared__ float xsT[64][68];
    int tid = threadIdx.x;
    int k0 = blockIdx.x * 64;
#pragma unroll
    for (int it = 0; it < 4; ++it) {
        int f = it * 256 + tid;
        int i = f >> 4, k4 = (f & 15) * 4;
        float4 v = *(const float4*)(X + (size_t)i * 16384 + k0 + k4);
        xsT[k4 + 0][i] = v.x; xsT[k4 + 1][i] = v.y;
        xsT[k4 + 2][i] = v.z; xsT[k4 + 3][i] = v.w;
    }
    __syncthreads();
    int ti = (tid >> 4) * 4, tj = (tid & 15) * 4;
    float4 a0 = make_float4(0, 0, 0, 0), a1 = a0, a2 = a0, a3 = a0;
#pragma unroll 8
    for (int k = 0; k < 64; ++k) {
        float4 a = *(const float4*)&xsT[k][ti];
        float4 b = *(const float4*)&xsT[k][tj];
        a0 = f4fma(a.x, b, a0); a1 = f4fma(a.y, b, a1);
        a2 = f4fma(a.z, b, a2); a3 = f4fma(a.w, b, a3);
    }
    float* r0 = adjraw + (ti + 0) * 64 + tj;
    float* r1 = adjraw + (ti + 1) * 64 + tj;
    float* r2 = adjraw + (ti + 2) * 64 + tj;
    float* r3 = adjraw + (ti + 3) * 64 + tj;
    atomicAdd(r0 + 0, a0.x); atomicAdd(r0 + 1, a0.y); atomicAdd(r0 + 2, a0.z); atomicAdd(r0 + 3, a0.w);
    atomicAdd(r1 + 0, a1.x); atomicAdd(r1 + 1, a1.y); atomicAdd(r1 + 2, a1.z); atomicAdd(r1 + 3, a1.w);
    atomicAdd(r2 + 0, a2.x); atomicAdd(r2 + 1, a2.y); atomicAdd(r2 + 2, a2.z); atomicAdd(r2 + 3, a2.w);
    atomicAdd(r3 + 0, a3.x); atomicAdd(r3 + 1, a3.y); atomicAdd(r3 + 2, a3.z); atomicAdd(r3 + 3, a3.w);
}

// ---------------------------------------------------------------------------
// K2: on-the-fly sparsemax of adjraw rows + agg0 + W0 projection + relu -> h0.
// 512 blocks = 64 t-chunks x 8 B-chunks; wave w handles B's Bc+2w, Bc+2w+1.
// x read directly from global (L2-resident); p rows via LDS broadcast.
// x is [B][T][E]=[64][256][64]: per-b stride = 16384 floats = 4096 float4s.
// (R5 bug: used 1024 float4s — the t-block stride, not the b stride.)
// ---------------------------------------------------------------------------
__global__ __launch_bounds__(256)
void agg0_kernel(const float* __restrict__ x, const float* __restrict__ adjraw,
                 const float* __restrict__ W0, float* __restrict__ h0) {
    __shared__ float psm[8 * 64];
    int tid = threadIdx.x;
    int lane = tid & 63;
    int w = __builtin_amdgcn_readfirstlane(tid >> 6);
    int t0 = (blockIdx.x >> 3) * 4;
    int Bc = (blockIdx.x & 7) * 8;
    // sparsemax rows Bc+2w, Bc+2w+1 (lane = element)
    {
        float zA = adjraw[(Bc + 2 * w) * 64 + lane] * (1.0f / 256.0f);
        float zB = adjraw[(Bc + 2 * w + 1) * 64 + lane] * (1.0f / 256.0f);
        psm[(2 * w) * 64 + lane] = wave_sparsemax(zA, lane);
        psm[(2 * w + 1) * 64 + lane] = wave_sparsemax(zB, lane);
    }
    // no __syncthreads: each wave reads only its own psm rows
    int t = lane >> 4, eq = lane & 15;
    const float* pA = psm + (2 * w) * 64;
    const float* pB = pA + 64;
    float4 w0r0 = *(const float4*)(W0 + (eq * 4 + 0) * 4);
    float4 w0r1 = *(const float4*)(W0 + (eq * 4 + 1) * 4);
    float4 w0r2 = *(const float4*)(W0 + (eq * 4 + 2) * 4);
    float4 w0r3 = *(const float4*)(W0 + (eq * 4 + 3) * 4);
    // xg[b * 4096]: x[(b*256 + t0+t)*64 + eq*4], b-stride 4096 float4s
    const float4* xg = (const float4*)(x + ((size_t)(t0 + t) * 64) + eq * 4);
    float4 x4 = xg[0];
    float4 vA = f4scale(pA[0], x4), vB = f4scale(pB[0], x4);
    float4 qm1A = vA, qm1B = vB;
    x4 = xg[4096];
    float4 vtA = f4scale(pA[1], x4), vtB = f4scale(pB[1], x4);
    float4 qbA = f4max(vA, vtA), qbB = f4max(vB, vtB);
    float4 accA = make_float4(0, 0, 0, 0), accB = accA;
#pragma unroll 8
    for (int bl = 0; bl < 62; ++bl) {
        x4 = xg[(size_t)(bl + 2) * 4096];
        float4 vnA = f4scale(pA[bl + 2], x4);
        float4 vnB = f4scale(pB[bl + 2], x4);
        float4 q1A = f4max(vtA, vnA), q1B = f4max(vtB, vnB);
        accA = f4add(accA, f4max(qm1A, q1A));
        accB = f4add(accB, f4max(qm1B, q1B));
        qm1A = qbA; qbA = q1A; vtA = vnA;
        qm1B = qbB; qbB = q1B; vtB = vnB;
    }
    accA = f4add(accA, f4max(qm1A, vtA));   // win[62] = max(q61, q63)
    accB = f4add(accB, f4max(qm1B, vtB));
    accA = f4add(accA, qbA);                // win[63] = q62
    accB = f4add(accB, qbB);
#pragma unroll
    for (int half = 0; half < 2; ++half) {
        float4 acc = half ? accB : accA;
        float4 h = f4fma(acc.x, w0r0, f4fma(acc.y, w0r1,
                   f4fma(acc.z, w0r2, f4scale(acc.w, w0r3))));
        for (int m = 1; m <= 8; m <<= 1) {
            h.x += __shfl_xor(h.x, m, 64);
            h.y += __shfl_xor(h.y, m, 64);
            h.z += __shfl_xor(h.z, m, 64);
            h.w += __shfl_xor(h.w, m, 64);
        }
        if (eq == 0) {
            int B = Bc + 2 * w + half;
            float4 r = make_float4(fmaxf(h.x, 0.f), fmaxf(h.y, 0.f),
                                   fmaxf(h.z, 0.f), fmaxf(h.w, 0.f));
            *(float4*)(h0 + (size_t)(B * 256 + t0 + t) * 4) = r;
        }
    }
}

// ---------------------------------------------------------------------------
// K3: block b: gram1 row b + sparsemax -> adj1 row (LDS only), then agg1 for
// batch b + W1 + relu + mean_t + softmax -> out[b]. No cross-block deps.
// ---------------------------------------------------------------------------
__global__ __launch_bounds__(256)
void tail_kernel(const float* __restrict__ h0, const float* __restrict__ W1,
                 const float* __restrict__ Wp, float* __restrict__ out) {
    __shared__ __align__(16) float row[4 * 260];  // h0[bid,:] padded per quarter
    __shared__ float part[256];
    __shared__ float psm[64];
    __shared__ float red[16];
    int tid = threadIdx.x;
    int lane = tid & 63;
    int bid = blockIdx.x;
    // stage own row, padded: flat s = q*256 + r  ->  row[q*260 + r]
    {
        int q = tid >> 6, s = (tid & 63) * 4;
        *(float4*)(row + q * 260 + s) = *(const float4*)(h0 + (size_t)bid * 1024 + tid * 4);
    }
    __syncthreads();
    // gram1: part[j*4+q] = partial dot(h0[bid,:], h0[j,:]) over quarter q
    {
        int j = tid >> 2, q = tid & 3;
        const float4* hj = (const float4*)(h0 + (size_t)j * 1024 + q * 256);
        const float4* ri = (const float4*)(row + q * 260);
        float4 s4 = make_float4(0, 0, 0, 0);
#pragma unroll 8
        for (int kk = 0; kk < 64; ++kk) s4 = f4fma4(ri[kk], hj[kk], s4);
        part[tid] = s4.x + s4.y + s4.z + s4.w;
    }
    __syncthreads();
    if (tid < 64) {
        float z = (part[lane * 4] + part[lane * 4 + 1] + part[lane * 4 + 2]
                   + part[lane * 4 + 3]) * (1.0f / 256.0f);
        psm[lane] = wave_sparsemax(z, lane);
    }
    __syncthreads();
    // agg1 for batch bid: wave w covers t in [w*64, w*64+64)
    int w = __builtin_amdgcn_readfirstlane(tid >> 6);
    int rc = lane & 3;
    float psum = 0.f;
#pragma unroll
    for (int gg = 0; gg < 4; ++gg) {
        int tbase = w * 64 + gg * 16;
        const float* xb = h0 + (size_t)tbase * 4 + lane;   // h0 b-stride 1024 floats
        float v0 = psm[0] * xb[0];
        float v1 = psm[1] * xb[1024];
        float qm1 = v0, qb = fmaxf(v0, v1), vt = v1, acc = 0.f;
#pragma unroll 8
        for (int bl = 0; bl < 62; ++bl) {
            float vn = psm[bl + 2] * xb[(size_t)(bl + 2) * 1024];
            float q1 = fmaxf(vt, vn);
            acc += fmaxf(qm1, q1);
            qm1 = qb; qb = q1; vt = vn;
        }
        acc += fmaxf(qm1, vt);
        acc += qb;
        int base = lane & ~3;
        float b0 = __shfl(acc, base + 0, 64);
        float b1 = __shfl(acc, base + 1, 64);
        float b2 = __shfl(acc, base + 2, 64);
        float b3 = __shfl(acc, base + 3, 64);
        float h = b0 * W1[rc] + b1 * W1[4 + rc] + b2 * W1[8 + rc] + b3 * W1[12 + rc];
        psum += fmaxf(h, 0.f);
    }
    for (int m = 4; m <= 32; m <<= 1) psum += __shfl_xor(psum, m, 64);
    if (lane < 4) red[w * 4 + lane] = psum;
    __syncthreads();
    if (tid < 64) {
        float pooled = 0.f;
        if (lane < 4)
            pooled = (red[lane] + red[4 + lane] + red[8 + lane] + red[12 + lane])
                     * (1.0f / 256.0f);
        float q0 = __shfl(pooled, 0, 64), q1 = __shfl(pooled, 1, 64);
        float q2 = __shfl(pooled, 2, 64), q3 = __shfl(pooled, 3, 64);
        float logit = -INFINITY;
        if (lane < 8)
            logit = q0 * Wp[lane] + q1 * Wp[8 + lane]
                  + q2 * Wp[16 + lane] + q3 * Wp[24 + lane];
        float mx = logit;
        for (int m = 4; m >= 1; m >>= 1) mx = fmaxf(mx, __shfl_xor(mx, m, 8));
        float e = (lane < 8) ? __expf(logit - mx) : 0.f;
        float s = e;
        for (int m = 4; m >= 1; m >>= 1) s += __shfl_xor(s, m, 8);
        if (lane < 8) out[bid * 8 + lane] = e / s;
    }
}

extern "C" void kernel_launch(void* const* d_in, const int* in_sizes, int n_in,
                              void* d_out, int out_size, void* d_ws, size_t ws_size,
                              hipStream_t stream) {
    const float* x  = (const float*)d_in[0];   // [64,256,64]
    const float* W0 = (const float*)d_in[1];   // [64,4]
    const float* W1 = (const float*)d_in[2];   // [4,4]
    const float* Wp = (const float*)d_in[3];   // [4,8]
    float* out = (float*)d_out;                // [64,8]

    char* ws = (char*)d_ws;
    float* adjraw = (float*)ws;                // 16 KB
    float* h0     = (float*)(ws + 16384);      // 256 KB

    hipMemsetAsync(adjraw, 0, 16384, stream);  // atomic accumulator must start at 0
    gram0_kernel<<<256, 256, 0, stream>>>(x, adjraw);
    agg0_kernel<<<512, 256, 0, stream>>>(x, adjraw, W0, h0);
    tail_kernel<<<64, 256, 0, stream>>>(h0, W1, Wp, out);
}

// Round 7
// 118.826 us; speedup vs baseline: 2.5372x; 1.1017x over previous
//
#include <hip/hip_runtime.h>
#include <math.h>

__device__ __forceinline__ float4 f4max(float4 a, float4 b) {
    return make_float4(fmaxf(a.x, b.x), fmaxf(a.y, b.y), fmaxf(a.z, b.z), fmaxf(a.w, b.w));
}
__device__ __forceinline__ float4 f4scale(float s, float4 v) {
    return make_float4(s * v.x, s * v.y, s * v.z, s * v.w);
}
__device__ __forceinline__ float4 f4add(float4 a, float4 b) {
    return make_float4(a.x + b.x, a.y + b.y, a.z + b.z, a.w + b.w);
}
__device__ __forceinline__ float4 f4fma(float a, float4 b, float4 c) {  // scalar*vec+vec
    return make_float4(fmaf(a, b.x, c.x), fmaf(a, b.y, c.y), fmaf(a, b.z, c.z), fmaf(a, b.w, c.w));
}
__device__ __forceinline__ float4 f4fma4(float4 a, float4 b, float4 c) { // elementwise
    return make_float4(fmaf(a.x, b.x, c.x), fmaf(a.y, b.y, c.y),
                       fmaf(a.z, b.z, c.z), fmaf(a.w, b.w, c.w));
}

// Wave-level sparsemax (verified R2-R6): lane holds element `lane` of a 64-vector.
__device__ __forceinline__ float wave_sparsemax(float z, int lane) {
    float v = z;
    for (int k = 2; k <= 64; k <<= 1) {
        bool desc = (lane & k) == 0;
        for (int j = k >> 1; j > 0; j >>= 1) {
            float other = __shfl_xor(v, j, 64);
            bool lower = (lane & j) == 0;
            float mn = fminf(v, other), mx = fmaxf(v, other);
            v = (desc ^ lower) ? mn : mx;
        }
    }
    float c = v;
    for (int d = 1; d < 64; d <<= 1) {
        float n = __shfl_up(c, d, 64);
        if (lane >= d) c += n;
    }
    bool sup = (1.0f + (float)(lane + 1) * v) > c;
    int ksel = __popcll(__ballot(sup));
    float zk = __shfl(c, ksel - 1, 64);
    float tau = (zk - 1.0f) / (float)ksel;
    return fmaxf(z - tau, 0.f);
}

// ---------------------------------------------------------------------------
// K1: gram partials, NO atomics (R6 post-mortem: 256-way-contended float
// atomics cost ~50+ us). P[c][i][j] = sum_{k in 64-chunk c} X[i][k]X[j][k].
// R3-verified: LDS-transposed staging, 4x4 register tile, 2 ds_read_b128/k.
// ---------------------------------------------------------------------------
__global__ __launch_bounds__(256)
void gram_partial(const float* __restrict__ X, float* __restrict__ P) {
    __shared__ float xsT[64][68];
    int tid = threadIdx.x;
    int k0 = blockIdx.x * 64;
#pragma unroll
    for (int it = 0; it < 4; ++it) {
        int f = it * 256 + tid;
        int i = f >> 4, k4 = (f & 15) * 4;
        float4 v = *(const float4*)(X + (size_t)i * 16384 + k0 + k4);
        xsT[k4 + 0][i] = v.x; xsT[k4 + 1][i] = v.y;
        xsT[k4 + 2][i] = v.z; xsT[k4 + 3][i] = v.w;
    }
    __syncthreads();
    int ti = (tid >> 4) * 4, tj = (tid & 15) * 4;
    float4 a0 = make_float4(0, 0, 0, 0), a1 = a0, a2 = a0, a3 = a0;
#pragma unroll 8
    for (int k = 0; k < 64; ++k) {
        float4 a = *(const float4*)&xsT[k][ti];
        float4 b = *(const float4*)&xsT[k][tj];
        a0 = f4fma(a.x, b, a0); a1 = f4fma(a.y, b, a1);
        a2 = f4fma(a.z, b, a2); a3 = f4fma(a.w, b, a3);
    }
    float* basep = P + ((size_t)blockIdx.x << 12);
    *(float4*)(basep + (ti + 0) * 64 + tj) = a0;
    *(float4*)(basep + (ti + 1) * 64 + tj) = a1;
    *(float4*)(basep + (ti + 2) * 64 + tj) = a2;
    *(float4*)(basep + (ti + 3) * 64 + tj) = a3;
}

// ---------------------------------------------------------------------------
// K2: reduce 256 partial chunks + sparsemax -> FINAL adj0. One block per row.
// (R3-verified structure.)
// ---------------------------------------------------------------------------
__global__ __launch_bounds__(256)
void reduce_sm(const float* __restrict__ P, float* __restrict__ adj0) {
    __shared__ float red[4 * 64];
    int tid = threadIdx.x;
    int row = blockIdx.x;
    int w = tid >> 6;
    int lane = tid & 63;
    float s = 0.f;
    for (int c = w * 64; c < (w + 1) * 64; ++c)
        s += P[((size_t)c << 12) + row * 64 + lane];
    red[w * 64 + lane] = s;
    __syncthreads();
    if (tid < 64) {
        float z = (red[lane] + red[64 + lane] + red[128 + lane] + red[192 + lane])
                  * (1.0f / 256.0f);
        adj0[row * 64 + lane] = wave_sparsemax(z, lane);
    }
}

// ---------------------------------------------------------------------------
// K3: agg0 + W0 projection + relu -> h0 (R6-verified, minus sparsemax —
// adj0 is already final). 512 blocks = 64 t-chunks x 8 B-chunks; wave w
// handles B's Bc+2w, Bc+2w+1. x b-stride = 4096 float4s (R6 fix).
// p rows read as uniform global scalars.
// ---------------------------------------------------------------------------
__global__ __launch_bounds__(256)
void agg0_kernel(const float* __restrict__ x, const float* __restrict__ adj0,
                 const float* __restrict__ W0, float* __restrict__ h0) {
    int tid = threadIdx.x;
    int lane = tid & 63;
    int w = __builtin_amdgcn_readfirstlane(tid >> 6);
    int t0 = (blockIdx.x >> 3) * 4;
    int Bc = (blockIdx.x & 7) * 8;
    int t = lane >> 4, eq = lane & 15;
    const float* pA = adj0 + (Bc + 2 * w) * 64;   // uniform -> scalar loads
    const float* pB = pA + 64;
    float4 w0r0 = *(const float4*)(W0 + (eq * 4 + 0) * 4);
    float4 w0r1 = *(const float4*)(W0 + (eq * 4 + 1) * 4);
    float4 w0r2 = *(const float4*)(W0 + (eq * 4 + 2) * 4);
    float4 w0r3 = *(const float4*)(W0 + (eq * 4 + 3) * 4);
    // xg[b * 4096]: x[(b*256 + t0+t)*64 + eq*4], b-stride 4096 float4s
    const float4* xg = (const float4*)(x + ((size_t)(t0 + t) * 64) + eq * 4);
    float4 x4 = xg[0];
    float4 vA = f4scale(pA[0], x4), vB = f4scale(pB[0], x4);
    float4 qm1A = vA, qm1B = vB;
    x4 = xg[4096];
    float4 vtA = f4scale(pA[1], x4), vtB = f4scale(pB[1], x4);
    float4 qbA = f4max(vA, vtA), qbB = f4max(vB, vtB);
    float4 accA = make_float4(0, 0, 0, 0), accB = accA;
#pragma unroll 8
    for (int bl = 0; bl < 62; ++bl) {
        x4 = xg[(size_t)(bl + 2) * 4096];
        float4 vnA = f4scale(pA[bl + 2], x4);
        float4 vnB = f4scale(pB[bl + 2], x4);
        float4 q1A = f4max(vtA, vnA), q1B = f4max(vtB, vnB);
        accA = f4add(accA, f4max(qm1A, q1A));
        accB = f4add(accB, f4max(qm1B, q1B));
        qm1A = qbA; qbA = q1A; vtA = vnA;
        qm1B = qbB; qbB = q1B; vtB = vnB;
    }
    accA = f4add(accA, f4max(qm1A, vtA));   // win[62] = max(q61, q63)
    accB = f4add(accB, f4max(qm1B, vtB));
    accA = f4add(accA, qbA);                // win[63] = q62
    accB = f4add(accB, qbB);
#pragma unroll
    for (int half = 0; half < 2; ++half) {
        float4 acc = half ? accB : accA;
        float4 h = f4fma(acc.x, w0r0, f4fma(acc.y, w0r1,
                   f4fma(acc.z, w0r2, f4scale(acc.w, w0r3))));
        for (int m = 1; m <= 8; m <<= 1) {
            h.x += __shfl_xor(h.x, m, 64);
            h.y += __shfl_xor(h.y, m, 64);
            h.z += __shfl_xor(h.z, m, 64);
            h.w += __shfl_xor(h.w, m, 64);
        }
        if (eq == 0) {
            int B = Bc + 2 * w + half;
            float4 r = make_float4(fmaxf(h.x, 0.f), fmaxf(h.y, 0.f),
                                   fmaxf(h.z, 0.f), fmaxf(h.w, 0.f));
            *(float4*)(h0 + (size_t)(B * 256 + t0 + t) * 4) = r;
        }
    }
}

// ---------------------------------------------------------------------------
// K4: block b: gram1 row b + sparsemax (LDS only), then agg1 + W1 + relu +
// mean_t + softmax -> out[b]. No cross-block deps. (R6-verified.)
// ---------------------------------------------------------------------------
__global__ __launch_bounds__(256)
void tail_kernel(const float* __restrict__ h0, const float* __restrict__ W1,
                 const float* __restrict__ Wp, float* __restrict__ out) {
    __shared__ __align__(16) float row[4 * 260];  // h0[bid,:] padded per quarter
    __shared__ float part[256];
    __shared__ float psm[64];
    __shared__ float red[16];
    int tid = threadIdx.x;
    int lane = tid & 63;
    int bid = blockIdx.x;
    {
        int q = tid >> 6, s = (tid & 63) * 4;
        *(float4*)(row + q * 260 + s) = *(const float4*)(h0 + (size_t)bid * 1024 + tid * 4);
    }
    __syncthreads();
    {
        int j = tid >> 2, q = tid & 3;
        const float4* hj = (const float4*)(h0 + (size_t)j * 1024 + q * 256);
        const float4* ri = (const float4*)(row + q * 260);
        float4 s4 = make_float4(0, 0, 0, 0);
#pragma unroll 8
        for (int kk = 0; kk < 64; ++kk) s4 = f4fma4(ri[kk], hj[kk], s4);
        part[tid] = s4.x + s4.y + s4.z + s4.w;
    }
    __syncthreads();
    if (tid < 64) {
        float z = (part[lane * 4] + part[lane * 4 + 1] + part[lane * 4 + 2]
                   + part[lane * 4 + 3]) * (1.0f / 256.0f);
        psm[lane] = wave_sparsemax(z, lane);
    }
    __syncthreads();
    int w = __builtin_amdgcn_readfirstlane(tid >> 6);
    int rc = lane & 3;
    float psum = 0.f;
#pragma unroll
    for (int gg = 0; gg < 4; ++gg) {
        int tbase = w * 64 + gg * 16;
        const float* xb = h0 + (size_t)tbase * 4 + lane;   // h0 b-stride 1024 floats
        float v0 = psm[0] * xb[0];
        float v1 = psm[1] * xb[1024];
        float qm1 = v0, qb = fmaxf(v0, v1), vt = v1, acc = 0.f;
#pragma unroll 8
        for (int bl = 0; bl < 62; ++bl) {
            float vn = psm[bl + 2] * xb[(size_t)(bl + 2) * 1024];
            float q1 = fmaxf(vt, vn);
            acc += fmaxf(qm1, q1);
            qm1 = qb; qb = q1; vt = vn;
        }
        acc += fmaxf(qm1, vt);
        acc += qb;
        int base = lane & ~3;
        float b0 = __shfl(acc, base + 0, 64);
        float b1 = __shfl(acc, base + 1, 64);
        float b2 = __shfl(acc, base + 2, 64);
        float b3 = __shfl(acc, base + 3, 64);
        float h = b0 * W1[rc] + b1 * W1[4 + rc] + b2 * W1[8 + rc] + b3 * W1[12 + rc];
        psum += fmaxf(h, 0.f);
    }
    for (int m = 4; m <= 32; m <<= 1) psum += __shfl_xor(psum, m, 64);
    if (lane < 4) red[w * 4 + lane] = psum;
    __syncthreads();
    if (tid < 64) {
        float pooled = 0.f;
        if (lane < 4)
            pooled = (red[lane] + red[4 + lane] + red[8 + lane] + red[12 + lane])
                     * (1.0f / 256.0f);
        float q0 = __shfl(pooled, 0, 64), q1 = __shfl(pooled, 1, 64);
        float q2 = __shfl(pooled, 2, 64), q3 = __shfl(pooled, 3, 64);
        float logit = -INFINITY;
        if (lane < 8)
            logit = q0 * Wp[lane] + q1 * Wp[8 + lane]
                  + q2 * Wp[16 + lane] + q3 * Wp[24 + lane];
        float mx = logit;
        for (int m = 4; m >= 1; m >>= 1) mx = fmaxf(mx, __shfl_xor(mx, m, 8));
        float e = (lane < 8) ? __expf(logit - mx) : 0.f;
        float s = e;
        for (int m = 4; m >= 1; m >>= 1) s += __shfl_xor(s, m, 8);
        if (lane < 8) out[bid * 8 + lane] = e / s;
    }
}

extern "C" void kernel_launch(void* const* d_in, const int* in_sizes, int n_in,
                              void* d_out, int out_size, void* d_ws, size_t ws_size,
                              hipStream_t stream) {
    const float* x  = (const float*)d_in[0];   // [64,256,64]
    const float* W0 = (const float*)d_in[1];   // [64,4]
    const float* W1 = (const float*)d_in[2];   // [4,4]
    const float* Wp = (const float*)d_in[3];   // [4,8]
    float* out = (float*)d_out;                // [64,8]

    char* ws = (char*)d_ws;
    float* P    = (float*)ws;                          // 4 MB partials
    float* adj0 = (float*)(ws + (4u << 20));           // 16 KB (final, sparsemaxed)
    float* h0   = (float*)(ws + (4u << 20) + 16384);   // 256 KB

    gram_partial<<<256, 256, 0, stream>>>(x, P);
    reduce_sm<<<64, 256, 0, stream>>>(P, adj0);
    agg0_kernel<<<512, 256, 0, stream>>>(x, adj0, W0, h0);
    tail_kernel<<<64, 256, 0, stream>>>(h0, W1, Wp, out);
}